// Round 3
// baseline (89.992 us; speedup 1.0000x reference)
//
#include <hip/hip_runtime.h>
#include <stdint.h>

#define B_SZ 2048
#define F_SZ 24
#define E_SZ 128
#define P_SZ 276            // F*(F-1)/2
#define BT   128            // batch rows per block
#define NB   (B_SZ / BT)    // 16
#define NWG  (P_SZ * NB)    // 4416

#define XB_ELEMS (B_SZ * F_SZ * E_SZ)   // 6,291,456  (12.6 MB bf16)
#define KB_ELEMS (P_SZ * E_SZ * E_SZ)   // 4,521,984  ( 9.0 MB bf16)
#define WS_NEED  ((size_t)(XB_ELEMS + KB_ELEMS) * 2)

typedef __bf16 bf16x8 __attribute__((ext_vector_type(8)));
typedef __bf16 bf16x4 __attribute__((ext_vector_type(4)));
typedef float  f32x16 __attribute__((ext_vector_type(16)));

// ---------------- prepack: x (f32) -> xb (bf16, same [B,F,E] layout) --------
__global__ __launch_bounds__(256) void prepack_x(
    const float* __restrict__ x, __bf16* __restrict__ xb)
{
    size_t g = (size_t)blockIdx.x * 256 + threadIdx.x;   // one 8-elem chunk
    const float4 v0 = *(const float4*)(x + g * 8);
    const float4 v1 = *(const float4*)(x + g * 8 + 4);
    bf16x8 h;
    h[0] = (__bf16)v0.x; h[1] = (__bf16)v0.y; h[2] = (__bf16)v0.z; h[3] = (__bf16)v0.w;
    h[4] = (__bf16)v1.x; h[5] = (__bf16)v1.y; h[6] = (__bf16)v1.z; h[7] = (__bf16)v1.w;
    *(bf16x8*)(xb + g * 8) = h;
}

// ---- prepack: kern [d,P,e] f32 -> Kb [P][d][e] bf16, PRE-SWIZZLED ----------
// Kb[p][d*128 + s*8 + i] = kern[(d*P+p)*128 + (s ^ (d&15))*8 + i]
// so a LINEAR global_load_lds copy yields the XOR-swizzled LDS image.
__global__ __launch_bounds__(256) void prepack_k(
    const float* __restrict__ kern, __bf16* __restrict__ kb)
{
    int g = blockIdx.x * 256 + threadIdx.x;   // 16B-slot id, 0..565247
    int p = g >> 11;                          // 2048 slots per pair
    int r = g & 2047;
    int d = r >> 4, s = r & 15;
    const float* src = kern + ((size_t)d * P_SZ + p) * E_SZ + ((s ^ (d & 15)) << 3);
    float4 v0 = *(const float4*)src;
    float4 v1 = *(const float4*)(src + 4);
    bf16x8 h;
    h[0] = (__bf16)v0.x; h[1] = (__bf16)v0.y; h[2] = (__bf16)v0.z; h[3] = (__bf16)v0.w;
    h[4] = (__bf16)v1.x; h[5] = (__bf16)v1.y; h[6] = (__bf16)v1.z; h[7] = (__bf16)v1.w;
    *(bf16x8*)(kb + (size_t)g * 8) = h;
}

// ---------------- main kernel ------------------------------------------------
__global__ __launch_bounds__(512, 6) void opn_main(
    const __bf16* __restrict__ xb,    // [B, F, E] bf16
    const __bf16* __restrict__ kb,    // [P][E][E] bf16, pre-swizzled
    float* __restrict__ out)          // [B, P] f32
{
    __shared__ short sB[E_SZ * E_SZ];   // swizzled K_p image, 32 KB
    __shared__ float red[2][BT];

    const int tid  = threadIdx.x;
    const int orig = blockIdx.x;
    // XCD (orig&7) owns batch quadrant qd (512 rows, xb slice 3.1MB -> L2-fits)
    // and pair half ph (138 pairs); pair-major, 4 batch sub-blocks adjacent.
    const int xcd = orig & 7, il = orig >> 3;      // il 0..551
    const int qd  = xcd >> 1, ph = xcd & 1;
    const int p   = ph * 138 + (il >> 2);
    const int b0  = qd * 512 + (il & 3) * BT;

    // p -> (fp, fq) for triu_indices(F, k=1)
    int fp = 0, rem = p;
    while (rem >= F_SZ - 1 - fp) { rem -= F_SZ - 1 - fp; ++fp; }
    const int fq = fp + 1 + rem;

    const int w = tid >> 6, lane = tid & 63;

    // ---- stage K_p via global_load_lds (linear copy of pre-swizzled image) --
    const __bf16* kp = kb + (size_t)p * (E_SZ * E_SZ);
#pragma unroll
    for (int t = 0; t < 4; ++t) {
        const int slot = (w * 4 + t) * 64 + lane;      // 16B-slot id
        __builtin_amdgcn_global_load_lds(
            (const __attribute__((address_space(1))) void*)(kp + slot * 8),
            (__attribute__((address_space(3))) void*)(&sB[(w * 4 + t) * 512]),
            16, 0, 0);
    }
    __syncthreads();

    const int l31 = lane & 31;
    const int hi  = lane >> 5;
    const int mh  = w >> 2;            // d-half (rows mh*64 .. +63)
    const int ng  = w & 3;             // batch group of 32
    const int brow = ng * 32 + l31;    // this lane's batch column (local)

    // ---- MFMA: T[d, b] = K_p[d,e] . Xp[b,e]^T ; B-frags straight from L2 ----
    const __bf16* xp_row = xb + ((size_t)(b0 + brow) * F_SZ + fp) * E_SZ;
    f32x16 acc[2];
#pragma unroll
    for (int mt = 0; mt < 2; ++mt)
#pragma unroll
        for (int j = 0; j < 16; ++j) acc[mt][j] = 0.f;

#pragma unroll
    for (int kk = 0; kk < 8; ++kk) {
        bf16x8 bfr = *(const bf16x8*)(xp_row + kk * 16 + hi * 8);
        const int e8 = kk * 2 + hi;
#pragma unroll
        for (int mt = 0; mt < 2; ++mt) {
            const int arow = (mh * 2 + mt) * 32 + l31;
            bf16x8 afr = *(const bf16x8*)&sB[arow * E_SZ + ((e8 ^ (arow & 15)) << 3)];
            acc[mt] = __builtin_amdgcn_mfma_f32_32x32x16_bf16(afr, bfr, acc[mt], 0, 0, 0);
        }
    }

    // ---- epilogue: s = sum_d T[d,b] * Xq[b,d]  (Xq bf16 from L2) ----
    // D layout: col = lane&31 (= b), row = (reg&3) + 8*(reg>>2) + 4*hi
    const __bf16* xq_row = xb + ((size_t)(b0 + brow) * F_SZ + fq) * E_SZ;
    float s = 0.f;
#pragma unroll
    for (int mt = 0; mt < 2; ++mt) {
        const int dbase = (mh * 2 + mt) * 32 + hi * 4;
#pragma unroll
        for (int q = 0; q < 4; ++q) {
            bf16x4 xq = *(const bf16x4*)(xq_row + dbase + q * 8);
            s += acc[mt][q * 4 + 0] * (float)xq[0] + acc[mt][q * 4 + 1] * (float)xq[1]
               + acc[mt][q * 4 + 2] * (float)xq[2] + acc[mt][q * 4 + 3] * (float)xq[3];
        }
    }
    s += __shfl_xor(s, 32);            // combine hi halves (k-rows of D)
    if (hi == 0) red[mh][brow] = s;
    __syncthreads();

    if (tid < BT)
        out[(size_t)(b0 + tid) * P_SZ + p] = red[0][tid] + red[1][tid];
}

// ---------------- fallback (round-2 kernel, used if ws too small) -----------
__global__ __launch_bounds__(512, 4) void opn_fallback(
    const float* __restrict__ x, const float* __restrict__ kern,
    float* __restrict__ out)
{
    __shared__ short sA[BT * E_SZ];
    __shared__ short sB[E_SZ * E_SZ];
    __shared__ float red[2][BT];

    const int tid = threadIdx.x;
    const int orig = blockIdx.x;
    const int wgid = (orig & 7) * (NWG / 8) + (orig >> 3);
    const int p  = wgid >> 4;
    const int bb = wgid & 15;
    const int b0 = bb * BT;

    int fp = 0, rem = p;
    while (rem >= F_SZ - 1 - fp) { rem -= F_SZ - 1 - fp; ++fp; }
    const int fq = fp + 1 + rem;

#pragma unroll
    for (int k = 0; k < 4; ++k) {
        int i = tid + k * 512;
        int r = i >> 4, s8 = i & 15;
        const float* src = x + ((size_t)(b0 + r) * F_SZ + fp) * E_SZ + s8 * 8;
        float4 v0 = *(const float4*)src;
        float4 v1 = *(const float4*)(src + 4);
        bf16x8 h;
        h[0] = (__bf16)v0.x; h[1] = (__bf16)v0.y; h[2] = (__bf16)v0.z; h[3] = (__bf16)v0.w;
        h[4] = (__bf16)v1.x; h[5] = (__bf16)v1.y; h[6] = (__bf16)v1.z; h[7] = (__bf16)v1.w;
        *(bf16x8*)&sA[r * E_SZ + ((s8 ^ (r & 15)) << 3)] = h;
    }
#pragma unroll
    for (int k = 0; k < 4; ++k) {
        int i = tid + k * 512;
        int r = i >> 4, s8 = i & 15;
        const float* src = kern + ((size_t)r * P_SZ + p) * E_SZ + s8 * 8;
        float4 v0 = *(const float4*)src;
        float4 v1 = *(const float4*)(src + 4);
        bf16x8 h;
        h[0] = (__bf16)v0.x; h[1] = (__bf16)v0.y; h[2] = (__bf16)v0.z; h[3] = (__bf16)v0.w;
        h[4] = (__bf16)v1.x; h[5] = (__bf16)v1.y; h[6] = (__bf16)v1.z; h[7] = (__bf16)v1.w;
        *(bf16x8*)&sB[r * E_SZ + ((s8 ^ (r & 15)) << 3)] = h;
    }
    __syncthreads();

    const int w = tid >> 6, lane = tid & 63;
    const int l31 = lane & 31, hi = lane >> 5;
    const int mh = w >> 2, ng = w & 3;

    f32x16 acc[2];
#pragma unroll
    for (int mt = 0; mt < 2; ++mt)
#pragma unroll
        for (int j = 0; j < 16; ++j) acc[mt][j] = 0.f;

    const int brow = ng * 32 + l31;
    const int bswz = brow * E_SZ;
#pragma unroll
    for (int kk = 0; kk < 8; ++kk) {
        const int e8 = kk * 2 + hi;
        bf16x8 bfr = *(const bf16x8*)&sA[bswz + ((e8 ^ (brow & 15)) << 3)];
#pragma unroll
        for (int mt = 0; mt < 2; ++mt) {
            int arow = (mh * 2 + mt) * 32 + l31;
            bf16x8 afr = *(const bf16x8*)&sB[arow * E_SZ + ((e8 ^ (arow & 15)) << 3)];
            acc[mt] = __builtin_amdgcn_mfma_f32_32x32x16_bf16(afr, bfr, acc[mt], 0, 0, 0);
        }
    }

    const float* xqp = x + ((size_t)(b0 + brow) * F_SZ + fq) * E_SZ;
    float s = 0.f;
#pragma unroll
    for (int mt = 0; mt < 2; ++mt) {
        const int dbase = (mh * 2 + mt) * 32 + hi * 4;
#pragma unroll
        for (int q = 0; q < 4; ++q) {
            float4 xq = *(const float4*)(xqp + dbase + q * 8);
            s += acc[mt][q * 4 + 0] * xq.x + acc[mt][q * 4 + 1] * xq.y
               + acc[mt][q * 4 + 2] * xq.z + acc[mt][q * 4 + 3] * xq.w;
        }
    }
    s += __shfl_xor(s, 32);
    if (hi == 0) red[mh][brow] = s;
    __syncthreads();

    if (tid < BT)
        out[(size_t)(b0 + tid) * P_SZ + p] = red[0][tid] + red[1][tid];
}

extern "C" void kernel_launch(void* const* d_in, const int* in_sizes, int n_in,
                              void* d_out, int out_size, void* d_ws, size_t ws_size,
                              hipStream_t stream) {
    const float* x    = (const float*)d_in[0];   // [2048, 24, 128] f32
    const float* kern = (const float*)d_in[1];   // [128, 276, 128] f32
    float* out = (float*)d_out;                  // [2048, 276] f32

    if (ws_size >= WS_NEED) {
        __bf16* xb = (__bf16*)d_ws;
        __bf16* kb = xb + XB_ELEMS;
        prepack_x<<<dim3(XB_ELEMS / 8 / 256), 256, 0, stream>>>(x, xb);
        prepack_k<<<dim3(KB_ELEMS / 8 / 256), 256, 0, stream>>>(kern, kb);
        opn_main<<<dim3(NWG), 512, 0, stream>>>(xb, kb, out);
    } else {
        opn_fallback<<<dim3(NWG), 512, 0, stream>>>(x, kern, out);
    }
}

// Round 4
// 57.160 us; speedup vs baseline: 1.5744x; 1.5744x over previous
//
#include <hip/hip_runtime.h>
#include <stdint.h>

#define B_SZ 2048
#define F_SZ 24
#define E_SZ 128
#define P_SZ 276            // F*(F-1)/2
#define BT   64             // batch rows per block
#define NB   (B_SZ / BT)    // 32
#define NWG  (P_SZ * NB)    // 8832 = 8 * 1104  (clean XCD split)

#define XB_ELEMS (B_SZ * F_SZ * E_SZ)   // 6,291,456  (12.6 MB bf16)
#define KB_ELEMS (P_SZ * E_SZ * E_SZ)   // 4,521,984  ( 9.0 MB bf16)
#define WS_NEED  ((size_t)(XB_ELEMS + KB_ELEMS) * 2)

#define XPREP_BLKS (XB_ELEMS / 2048)    // 3072 (256 thr x 8 elems)
#define KPREP_BLKS (KB_ELEMS / 2048)    // 2208

typedef __bf16 bf16x8 __attribute__((ext_vector_type(8)));
typedef __bf16 bf16x4 __attribute__((ext_vector_type(4)));
typedef float  f32x16 __attribute__((ext_vector_type(16)));

// ---- fused prepack: x -> xb (bf16 cast, same layout);
//      kern [d,P,e] f32 -> kb [P][d][e] bf16, PRE-SWIZZLED so a linear
//      LDS copy yields the XOR-swizzled image (slot s of row d holds
//      source slot s ^ (d&15)).
__global__ __launch_bounds__(256) void prepack_all(
    const float* __restrict__ x, const float* __restrict__ kern,
    __bf16* __restrict__ xb, __bf16* __restrict__ kb)
{
    const int bid = blockIdx.x;
    if (bid < XPREP_BLKS) {
        size_t g = (size_t)bid * 256 + threadIdx.x;      // 8-elem chunk
        float4 v0 = *(const float4*)(x + g * 8);
        float4 v1 = *(const float4*)(x + g * 8 + 4);
        bf16x8 h;
        h[0] = (__bf16)v0.x; h[1] = (__bf16)v0.y; h[2] = (__bf16)v0.z; h[3] = (__bf16)v0.w;
        h[4] = (__bf16)v1.x; h[5] = (__bf16)v1.y; h[6] = (__bf16)v1.z; h[7] = (__bf16)v1.w;
        *(bf16x8*)(xb + g * 8) = h;
    } else {
        int g = (bid - XPREP_BLKS) * 256 + threadIdx.x;  // 16B-slot id
        int p = g >> 11;                                 // 2048 slots/pair
        int r = g & 2047;
        int d = r >> 4, s = r & 15;
        const float* src = kern + ((size_t)d * P_SZ + p) * E_SZ + ((s ^ (d & 15)) << 3);
        float4 v0 = *(const float4*)src;
        float4 v1 = *(const float4*)(src + 4);
        bf16x8 h;
        h[0] = (__bf16)v0.x; h[1] = (__bf16)v0.y; h[2] = (__bf16)v0.z; h[3] = (__bf16)v0.w;
        h[4] = (__bf16)v1.x; h[5] = (__bf16)v1.y; h[6] = (__bf16)v1.z; h[7] = (__bf16)v1.w;
        *(bf16x8*)(kb + (size_t)g * 8) = h;
    }
}

// ---- main: one block = (pair p, 64-batch tile). All global traffic is
//      coalesced global_load_lds; all fragment reads from swizzled LDS.
__global__ __launch_bounds__(256, 2) void opn_main(
    const __bf16* __restrict__ xb,    // [B, F, E] bf16
    const __bf16* __restrict__ kb,    // [P][E][E] bf16, pre-swizzled
    float* __restrict__ out)          // [B, P] f32
{
    __shared__ short sK[E_SZ * E_SZ];   // 32 KB swizzled K_p
    __shared__ short sP[BT * E_SZ];     // 16 KB swizzled Xp
    __shared__ short sQ[BT * E_SZ];     // 16 KB swizzled Xq
    __shared__ float red[2][BT];

    const int tid  = threadIdx.x;
    const int w    = tid >> 6, lane = tid & 63;
    const int orig = blockIdx.x;
    // XCD (orig&7) owns 4 batch-tiles (256 rows: xb slice 1.6MB, L2-fits)
    // x all 276 pairs; pair-major so the 4 sharers of K_p run adjacent.
    const int xcd = orig & 7, il = orig >> 3;   // il 0..1103
    const int p   = il >> 2;
    const int b0  = (xcd * 4 + (il & 3)) * BT;

    // p -> (fp, fq) for triu_indices(F, k=1)
    int fp = 0, rem = p;
    while (rem >= F_SZ - 1 - fp) { rem -= F_SZ - 1 - fp; ++fp; }
    const int fq = fp + 1 + rem;

    // ---- stage K_p: linear copy of pre-swizzled image (8 x 16B per lane) ----
    const __bf16* kp = kb + (size_t)p * (E_SZ * E_SZ);
#pragma unroll
    for (int t = 0; t < 8; ++t) {
        const int base = t * 256 + w * 64;             // wave-uniform slot base
        __builtin_amdgcn_global_load_lds(
            (const __attribute__((address_space(1))) void*)(kp + (size_t)(base + lane) * 8),
            (__attribute__((address_space(3))) void*)(&sK[base * 8]),
            16, 0, 0);
    }
    // ---- stage Xp / Xq: per-lane row-gather source (16 lanes contiguous per
    //      row -> 8 full 128B lines per wave-load), XOR swizzle folded into
    //      the SOURCE slot; LDS dest stays linear. ----
    const __bf16* xpg = xb + ((size_t)b0 * F_SZ + fp) * E_SZ;
    const __bf16* xqg = xb + ((size_t)b0 * F_SZ + fq) * E_SZ;
#pragma unroll
    for (int t = 0; t < 4; ++t) {
        const int base = t * 256 + w * 64;
        const int slot = base + lane;
        const int r = slot >> 4, s = slot & 15;
        const int ss = s ^ (r & 15);
        const size_t soff = (size_t)r * (F_SZ * E_SZ) + ss * 8;
        __builtin_amdgcn_global_load_lds(
            (const __attribute__((address_space(1))) void*)(xpg + soff),
            (__attribute__((address_space(3))) void*)(&sP[base * 8]),
            16, 0, 0);
        __builtin_amdgcn_global_load_lds(
            (const __attribute__((address_space(1))) void*)(xqg + soff),
            (__attribute__((address_space(3))) void*)(&sQ[base * 8]),
            16, 0, 0);
    }
    __syncthreads();

    const int l31 = lane & 31;
    const int hi  = lane >> 5;
    const int mh  = w >> 1;            // d-half (rows mh*64 .. +63)
    const int ng  = w & 1;             // batch group of 32
    const int brow = ng * 32 + l31;    // this lane's batch column (local)

    // ---- MFMA: T[d, b] = K_p[d,e] . Xp[b,e]^T ----
    // 32x32x16: a/b-frag lane&31 = row/col, k = (lane>>5)*8 + i
    f32x16 acc[2];
#pragma unroll
    for (int mt = 0; mt < 2; ++mt)
#pragma unroll
        for (int j = 0; j < 16; ++j) acc[mt][j] = 0.f;

#pragma unroll
    for (int kk = 0; kk < 8; ++kk) {
        const int e8 = kk * 2 + hi;
        bf16x8 bfr = *(const bf16x8*)&sP[brow * E_SZ + ((e8 ^ (brow & 15)) << 3)];
#pragma unroll
        for (int mt = 0; mt < 2; ++mt) {
            const int arow = (mh * 2 + mt) * 32 + l31;
            bf16x8 afr = *(const bf16x8*)&sK[arow * E_SZ + ((e8 ^ (arow & 15)) << 3)];
            acc[mt] = __builtin_amdgcn_mfma_f32_32x32x16_bf16(afr, bfr, acc[mt], 0, 0, 0);
        }
    }

    // ---- epilogue: s = sum_d T[d,b] * Xq[b,d], Xq from swizzled LDS ----
    // D layout: col = lane&31 (= b), row(d) = (reg&3) + 8*(reg>>2) + 4*hi
    float s = 0.f;
#pragma unroll
    for (int mt = 0; mt < 2; ++mt) {
#pragma unroll
        for (int q = 0; q < 4; ++q) {
            const int slotq = (mh * 2 + mt) * 4 + q;   // d = 32*tile + 8q + 4hi
            bf16x4 xq = *(const bf16x4*)&sQ[brow * E_SZ + ((slotq ^ (brow & 15)) << 3) + hi * 4];
            s += acc[mt][q * 4 + 0] * (float)xq[0] + acc[mt][q * 4 + 1] * (float)xq[1]
               + acc[mt][q * 4 + 2] * (float)xq[2] + acc[mt][q * 4 + 3] * (float)xq[3];
        }
    }
    s += __shfl_xor(s, 32);            // combine hi halves (k/row groups)
    if (hi == 0) red[mh][brow] = s;
    __syncthreads();

    if (tid < BT)
        out[(size_t)(b0 + tid) * P_SZ + p] = red[0][tid] + red[1][tid];
}

// ---------------- fallback (round-2 kernel, used if ws too small) -----------
__global__ __launch_bounds__(512, 4) void opn_fallback(
    const float* __restrict__ x, const float* __restrict__ kern,
    float* __restrict__ out)
{
    __shared__ short sA[128 * E_SZ];
    __shared__ short sB[E_SZ * E_SZ];
    __shared__ float red[2][128];

    const int tid = threadIdx.x;
    const int orig = blockIdx.x;
    const int nwg2 = P_SZ * 16;
    const int wgid = (orig & 7) * (nwg2 / 8) + (orig >> 3);
    const int p  = wgid >> 4;
    const int bb = wgid & 15;
    const int b0 = bb * 128;

    int fp = 0, rem = p;
    while (rem >= F_SZ - 1 - fp) { rem -= F_SZ - 1 - fp; ++fp; }
    const int fq = fp + 1 + rem;

#pragma unroll
    for (int k = 0; k < 4; ++k) {
        int i = tid + k * 512;
        int r = i >> 4, s8 = i & 15;
        const float* src = x + ((size_t)(b0 + r) * F_SZ + fp) * E_SZ + s8 * 8;
        float4 v0 = *(const float4*)src;
        float4 v1 = *(const float4*)(src + 4);
        bf16x8 h;
        h[0] = (__bf16)v0.x; h[1] = (__bf16)v0.y; h[2] = (__bf16)v0.z; h[3] = (__bf16)v0.w;
        h[4] = (__bf16)v1.x; h[5] = (__bf16)v1.y; h[6] = (__bf16)v1.z; h[7] = (__bf16)v1.w;
        *(bf16x8*)&sA[r * E_SZ + ((s8 ^ (r & 15)) << 3)] = h;
    }
#pragma unroll
    for (int k = 0; k < 4; ++k) {
        int i = tid + k * 512;
        int r = i >> 4, s8 = i & 15;
        const float* src = kern + ((size_t)r * P_SZ + p) * E_SZ + s8 * 8;
        float4 v0 = *(const float4*)src;
        float4 v1 = *(const float4*)(src + 4);
        bf16x8 h;
        h[0] = (__bf16)v0.x; h[1] = (__bf16)v0.y; h[2] = (__bf16)v0.z; h[3] = (__bf16)v0.w;
        h[4] = (__bf16)v1.x; h[5] = (__bf16)v1.y; h[6] = (__bf16)v1.z; h[7] = (__bf16)v1.w;
        *(bf16x8*)&sB[r * E_SZ + ((s8 ^ (r & 15)) << 3)] = h;
    }
    __syncthreads();

    const int w = tid >> 6, lane = tid & 63;
    const int l31 = lane & 31, hi = lane >> 5;
    const int mh = w >> 2, ng = w & 3;

    f32x16 acc[2];
#pragma unroll
    for (int mt = 0; mt < 2; ++mt)
#pragma unroll
        for (int j = 0; j < 16; ++j) acc[mt][j] = 0.f;

    const int brow = ng * 32 + l31;
#pragma unroll
    for (int kk = 0; kk < 8; ++kk) {
        const int e8 = kk * 2 + hi;
        bf16x8 bfr = *(const bf16x8*)&sA[brow * E_SZ + ((e8 ^ (brow & 15)) << 3)];
#pragma unroll
        for (int mt = 0; mt < 2; ++mt) {
            int arow = (mh * 2 + mt) * 32 + l31;
            bf16x8 afr = *(const bf16x8*)&sB[arow * E_SZ + ((e8 ^ (arow & 15)) << 3)];
            acc[mt] = __builtin_amdgcn_mfma_f32_32x32x16_bf16(afr, bfr, acc[mt], 0, 0, 0);
        }
    }

    const float* xqp = x + ((size_t)(b0 + brow) * F_SZ + fq) * E_SZ;
    float s = 0.f;
#pragma unroll
    for (int mt = 0; mt < 2; ++mt) {
        const int dbase = (mh * 2 + mt) * 32 + hi * 4;
#pragma unroll
        for (int q = 0; q < 4; ++q) {
            float4 xq = *(const float4*)(xqp + dbase + q * 8);
            s += acc[mt][q * 4 + 0] * xq.x + acc[mt][q * 4 + 1] * xq.y
               + acc[mt][q * 4 + 2] * xq.z + acc[mt][q * 4 + 3] * xq.w;
        }
    }
    s += __shfl_xor(s, 32);
    if (hi == 0) red[mh][brow] = s;
    __syncthreads();

    if (tid < 128)
        out[(size_t)(b0 + tid) * P_SZ + p] = red[0][tid] + red[1][tid];
}

extern "C" void kernel_launch(void* const* d_in, const int* in_sizes, int n_in,
                              void* d_out, int out_size, void* d_ws, size_t ws_size,
                              hipStream_t stream) {
    const float* x    = (const float*)d_in[0];   // [2048, 24, 128] f32
    const float* kern = (const float*)d_in[1];   // [128, 276, 128] f32
    float* out = (float*)d_out;                  // [2048, 276] f32

    if (ws_size >= WS_NEED) {
        __bf16* xb = (__bf16*)d_ws;
        __bf16* kb = xb + XB_ELEMS;
        prepack_all<<<dim3(XPREP_BLKS + KPREP_BLKS), 256, 0, stream>>>(x, kern, xb, kb);
        opn_main<<<dim3(NWG), 256, 0, stream>>>(xb, kb, out);
    } else {
        opn_fallback<<<dim3(P_SZ * 16), 512, 0, stream>>>(x, kern, out);
    }
}